// Round 9
// baseline (10382.874 us; speedup 1.0000x reference)
//
#include <hip/hip_runtime.h>
#include <hip/hip_bf16.h>

#define BATCH 16384
#define TSTEPS 101
#define HDIM 512
#define GDIM 2048
#define NBLK 256

typedef __attribute__((ext_vector_type(8))) short s16x8;
typedef __attribute__((ext_vector_type(16))) float f32x16;
typedef __attribute__((ext_vector_type(4))) float f32x4;

__device__ __forceinline__ float sigm(float x){
  return __builtin_amdgcn_rcpf(1.0f + __expf(-x));
}
__device__ __forceinline__ float tanhx(float x){
  float e = __expf(2.0f*x);
  return 1.0f - 2.0f*__builtin_amdgcn_rcpf(e + 1.0f);
}
__device__ __forceinline__ unsigned short bfr(float x){
  __hip_bfloat16 h = __float2bfloat16(x);
  return *reinterpret_cast<unsigned short*>(&h);
}

__device__ __forceinline__ void gload16(const void* g, void* l){
  __builtin_amdgcn_global_load_lds((const __attribute__((address_space(1))) unsigned int*)g,
                                   (__attribute__((address_space(3))) unsigned int*)l, 16, 0, 0);
}

// device-scope grid barrier (generation-based), proven in R5. 256 blocks, 1/CU.
__device__ __forceinline__ void gsync(unsigned* cnt, unsigned* gen){
  __syncthreads();
  if (threadIdx.x == 0){
    __threadfence();
    unsigned g = __hip_atomic_load(gen, __ATOMIC_RELAXED, __HIP_MEMORY_SCOPE_AGENT);
    unsigned prev = __hip_atomic_fetch_add(cnt, 1u, __ATOMIC_ACQ_REL, __HIP_MEMORY_SCOPE_AGENT);
    if (prev == NBLK - 1u){
      __hip_atomic_store(cnt, 0u, __ATOMIC_RELAXED, __HIP_MEMORY_SCOPE_AGENT);
      __hip_atomic_store(gen, g + 1u, __ATOMIC_RELEASE, __HIP_MEMORY_SCOPE_AGENT);
    } else {
      while (__hip_atomic_load(gen, __ATOMIC_ACQUIRE, __HIP_MEMORY_SCOPE_AGENT) == g){
        __builtin_amdgcn_s_sleep(8);
      }
    }
    __threadfence();
  }
  __syncthreads();
}

// Persistent fused LSTM: 256 blocks x 512 thr (8 waves), 1 block/CU (LDS 128KB).
// Block = (panel of 1024 batch rows, 32 hcols x 4 gates). W slice resident in LDS
// for all 101 steps; c resident in VGPRs; h round-trips through L2 (XCD-pinned).
// Wave = 32 rows x 128 gatecols per chunk; 4 chunks cover the panel.
// MFMA 32x32x16; C/D map: col=lane&31, row=(reg&3)+8*(reg>>2)+4*(lane>>5).
__global__ __launch_bounds__(512, 2) void lstm_fused(
    const float* __restrict__ bx,
    const float* __restrict__ Wih,
    const float* __restrict__ Whh,
    const float* __restrict__ bcomb,
    __hip_bfloat16* __restrict__ hb0,
    __hip_bfloat16* __restrict__ hb1,
    unsigned* cnt, unsigned* gen)
{
  __shared__ short sW[64*128*8];   // [k-oct 0..63][gaterow 0..127] x 16B = 128 KiB

  const int tid = threadIdx.x;
  const int l = tid & 63, w = tid >> 6;
  const int lo = l & 31, hi = l >> 5;

  const int b = blockIdx.x;
  const int panel = (b & 7)*2 + ((b >> 3) & 1);   // 16 panels x 1024 rows, XCD-pinned
  const int j = b >> 4;                           // 16 col-blocks x 32 hcols

  // ---- one-time: W slice -> LDS (fp32 -> bf16), transposed [oct][gaterow] ----
  #pragma unroll
  for (int i = 0; i < 16; ++i){
    int idx = i*512 + tid;                        // 8192 x 16B chunks
    int oct = idx >> 7, gr = idx & 127;
    const float* src = Whh + (size_t)((gr >> 5)*HDIM + j*32 + (gr & 31))*HDIM + oct*8;
    float4 f0 = *(const float4*)(src);
    float4 f1 = *(const float4*)(src + 4);
    s16x8 v;
    v[0]=(short)bfr(f0.x); v[1]=(short)bfr(f0.y); v[2]=(short)bfr(f0.z); v[3]=(short)bfr(f0.w);
    v[4]=(short)bfr(f1.x); v[5]=(short)bfr(f1.y); v[6]=(short)bfr(f1.z); v[7]=(short)bfr(f1.w);
    *(s16x8*)&sW[idx*8] = v;
  }
  __syncthreads();

  // t-invariant epilogue params
  const int colg = j*32 + lo;
  float4 wv4[4]; float bc4[4];
  #pragma unroll
  for (int g = 0; g < 4; ++g){
    wv4[g] = *(const float4*)(Wih + (size_t)(g*HDIM + colg)*4);
    bc4[g] = bcomb[g*HDIM + colg];
  }

  float cst[4][16];                // c state, VGPR-resident, statically indexed
  #pragma unroll
  for (int a = 0; a < 4; ++a)
    #pragma unroll
    for (int r = 0; r < 16; ++r) cst[a][r] = 0.f;

  for (int t = 0; t < TSTEPS; ++t){
    const __hip_bfloat16* hin = (t & 1) ? hb1 : hb0;
    __hip_bfloat16*      hout = (t & 1) ? hb0 : hb1;

    #pragma unroll
    for (int ch = 0; ch < 4; ++ch){
      f32x16 acc[4] = {};          // [gate]
      if (t > 0){
        const __hip_bfloat16* ap = hin + (size_t)(panel*1024 + ch*256 + w*32 + lo)*HDIM + hi*8;
        #pragma unroll
        for (int kt = 0; kt < 32; ++kt){
          s16x8 av = *(const s16x8*)(ap + kt*16);
          #pragma unroll
          for (int g = 0; g < 4; ++g){
            s16x8 bv = *(const s16x8*)&sW[(((kt*2 + hi) << 7) + g*32 + lo)*8];
            acc[g] = __builtin_amdgcn_mfma_f32_32x32x16_bf16(av, bv, acc[g], 0, 0, 0);
          }
        }
      }
      // ---- epilogue for this chunk (lane-local; c in regs) ----
      #pragma unroll
      for (int reg = 0; reg < 16; ++reg){
        const int row32 = (reg & 3) + 8*(reg >> 2) + 4*hi;
        const int r = panel*1024 + ch*256 + w*32 + row32;
        float4 xv = *(const float4*)(bx + ((size_t)r*TSTEPS + t)*4);
        float pi = acc[0][reg] + bc4[0] + xv.x*wv4[0].x + xv.y*wv4[0].y + xv.z*wv4[0].z + xv.w*wv4[0].w;
        float pf = acc[1][reg] + bc4[1] + xv.x*wv4[1].x + xv.y*wv4[1].y + xv.z*wv4[1].z + xv.w*wv4[1].w;
        float pg = acc[2][reg] + bc4[2] + xv.x*wv4[2].x + xv.y*wv4[2].y + xv.z*wv4[2].z + xv.w*wv4[2].w;
        float po = acc[3][reg] + bc4[3] + xv.x*wv4[3].x + xv.y*wv4[3].y + xv.z*wv4[3].z + xv.w*wv4[3].w;
        float iv = sigm(pi), fv = sigm(pf), gv = tanhx(pg), ov = sigm(po);
        float cn = fv*cst[ch][reg] + iv*gv;
        cst[ch][reg] = cn;
        hout[(size_t)r*HDIM + colg] = __float2bfloat16(ov*tanhx(cn));
      }
    }
    if (t < TSTEPS - 1) gsync(cnt, gen);
  }
}

__global__ void prep(const float* __restrict__ W1,
                     const float* __restrict__ bih, const float* __restrict__ bhh,
                     __hip_bfloat16* __restrict__ w1bf, float* __restrict__ bcomb){
  int i = blockIdx.x*256 + threadIdx.x;
  if (i < HDIM*HDIM) w1bf[i] = __float2bfloat16(W1[i]);
  if (i < GDIM) bcomb[i] = bih[i] + bhh[i];
}

// x = relu(hT @ W1^T + b1), bf16 MFMA, fp32 out. Block 128x128, wave 32x128.
__global__ __launch_bounds__(256) void mlp1(const __hip_bfloat16* __restrict__ hT,
                                            const __hip_bfloat16* __restrict__ w1bf,
                                            const float* __restrict__ b1, float* __restrict__ xout){
  __shared__ short sA[128*64];
  __shared__ short sB[128*64];
  const int tid = threadIdx.x;
  const int l = tid & 63, w = tid >> 6;
  const int lr = l & 15, lk = l >> 4;
  const int r0 = blockIdx.x * 128, c0 = blockIdx.y * 128;

  f32x4 acc[2][8] = {};
  for (int k0 = 0; k0 < HDIM; k0 += 64){
    __syncthreads();
    #pragma unroll
    for (int i = 0; i < 4; ++i){
      int cch = i*256 + tid;
      int row = cch >> 3, kc = cch & 7;
      int kcs = kc ^ (row & 7);
      gload16(hT + (size_t)(r0 + row)*HDIM + k0 + kcs*8, &sA[cch*8]);
    }
    #pragma unroll
    for (int i = 0; i < 4; ++i){
      int cch = i*256 + tid;
      int row = cch >> 3, kc = cch & 7;
      int kcs = kc ^ (row & 7);
      gload16(w1bf + (size_t)(c0 + row)*HDIM + k0 + kcs*8, &sB[cch*8]);
    }
    __syncthreads();
    #pragma unroll
    for (int kk = 0; kk < 2; ++kk){
      s16x8 av[2];
      #pragma unroll
      for (int m = 0; m < 2; ++m){
        int row = w*32 + m*16 + lr;
        int slot = row*8 + ((kk*4 + lk) ^ (row & 7));
        av[m] = *(const s16x8*)&sA[slot*8];
      }
      #pragma unroll
      for (int n = 0; n < 8; ++n){
        int rB = n*16 + lr;
        int slot = rB*8 + ((kk*4 + lk) ^ (rB & 7));
        s16x8 bv = *(const s16x8*)&sB[slot*8];
        #pragma unroll
        for (int m = 0; m < 2; ++m)
          acc[m][n] = __builtin_amdgcn_mfma_f32_16x16x32_bf16(av[m], bv, acc[m][n], 0, 0, 0);
      }
    }
  }
  #pragma unroll
  for (int m = 0; m < 2; ++m){
    #pragma unroll
    for (int rg = 0; rg < 4; ++rg){
      int r = r0 + w*32 + m*16 + lk*4 + rg;
      #pragma unroll
      for (int n = 0; n < 8; ++n){
        int c = c0 + n*16 + lr;
        float v = acc[m][n][rg] + b1[c];
        xout[(size_t)r*HDIM + c] = v > 0.f ? v : 0.f;
      }
    }
  }
}

// out[b] = x[b,:] . W2[0:512] + a[b]*W2[512] + b2 ; one wave per row
__global__ __launch_bounds__(256) void mlp2(const float* __restrict__ x, const float* __restrict__ a,
                                            const float* __restrict__ W2, const float* __restrict__ b2,
                                            float* __restrict__ out){
  const int wi = threadIdx.x >> 6, l = threadIdx.x & 63;
  const int b = blockIdx.x*4 + wi;
  const float* xr = x + (size_t)b*HDIM;
  float4 v0 = *(const float4*)(xr + l*8);
  float4 v1 = *(const float4*)(xr + l*8 + 4);
  float4 w0 = *(const float4*)(W2 + l*8);
  float4 w1 = *(const float4*)(W2 + l*8 + 4);
  float s = v0.x*w0.x + v0.y*w0.y + v0.z*w0.z + v0.w*w0.w
          + v1.x*w1.x + v1.y*w1.y + v1.z*w1.z + v1.w*w1.w;
  #pragma unroll
  for (int off = 32; off > 0; off >>= 1) s += __shfl_down(s, off);
  if (l == 0) out[b] = s + a[b]*W2[HDIM] + b2[0];
}

extern "C" void kernel_launch(void* const* d_in, const int* in_sizes, int n_in,
                              void* d_out, int out_size, void* d_ws, size_t ws_size,
                              hipStream_t stream){
  const float* bx  = (const float*)d_in[0];
  const float* ba  = (const float*)d_in[1];
  const float* Wih = (const float*)d_in[2];
  const float* Whh = (const float*)d_in[3];
  const float* bih = (const float*)d_in[4];
  const float* bhh = (const float*)d_in[5];
  const float* W1  = (const float*)d_in[6];
  const float* b1  = (const float*)d_in[7];
  const float* W2  = (const float*)d_in[8];
  const float* b2  = (const float*)d_in[9];
  float* out = (float*)d_out;

  char* ws = (char*)d_ws;
  __hip_bfloat16* w1bf  = (__hip_bfloat16*)(ws);              // 512 KB
  float*          bcomb = (float*)(ws + 524288);              // 8 KB
  __hip_bfloat16* hb0   = (__hip_bfloat16*)(ws + 532480);     // 16 MB
  __hip_bfloat16* hb1   = (__hip_bfloat16*)(ws + 17309696);   // 16 MB
  unsigned*       sync  = (unsigned*)(ws + 34086912);         // 256 B
  float*          xmlp  = (float*)(ws + 34087168);            // 32 MB (end ~66.5 MB)

  prep<<<1024, 256, 0, stream>>>(W1, bih, bhh, w1bf, bcomb);
  hipMemsetAsync(sync, 0, 256, stream);   // cnt=0, gen=0

  lstm_fused<<<NBLK, 512, 0, stream>>>(bx, Wih, Whh, bcomb, hb0, hb1,
                                       sync, sync + 32);

  // t=100 wrote hout = hb1
  mlp1<<<dim3(128, 4), 256, 0, stream>>>(hb1, w1bf, b1, xmlp);
  mlp2<<<4096, 256, 0, stream>>>(xmlp, ba, W2, b2, out);
}